// Round 3
// baseline (605.708 us; speedup 1.0000x reference)
//
#include <hip/hip_runtime.h>
#include <hip/hip_bf16.h>
#include <math.h>

// Problem dims (fixed by reference)
#define Bq 4
#define Nq 512
#define Cq 128   // d_in
#define Oq 64    // d_mid
#define TI 16
#define TJ 8
#define NPAIR (TI*TJ)               // 128 pairs per block
#define NBLK (Bq*(Nq/TI)*(Nq/TJ))   // 8192 pair-blocks
#define PTOT ((double)Bq*Nq*Nq)     // 1048576 pairs (BN2d population)
#define NROW (Bq*Nq)                // 2048 rows
#define EPSq 1e-5f
#define NEGq -9e15f

// ---- workspace layout (bytes, all 256-aligned) ----
#define OFF_S       0u                    // s / A in-place: 4*512*512*4 = 4 MiB
#define OFF_YAGG    4194304u              // [2048][128] f32
#define OFF_YFC     5242880u              // [2048][128] f32
#define OFF_WGT     6291456u              // WgT [128][128] f32
#define OFF_WTT     6356992u              // WtT [256][128] f32
#define OFF_W1T     6488064u              // W1T [128][64] f32
#define OFF_PART1   6520832u              // partial1 [8192][128] f32
#define OFF_RED1    10715136u             // double[128]
#define OFF_SC1     10716160u             // float scale1[64], shift1[64]
#define OFF_STATSG  10716672u             // double[256]
#define OFF_SCG     10718720u             // float scaleg[128], shiftg[128]
#define OFF_H       10719744u             // optional hT buffer [8192][64][128] f32
#define H_BYTES     268435456ull
#define WS_BASIC    (size_t)(OFF_H)
#define WS_WITH_H   ((size_t)OFF_H + H_BYTES)

__device__ __forceinline__ float lrelu(float v) { return v >= 0.0f ? v : 0.01f * v; }

// Common epilogue: per-lane acc[2 pairs][16 outputs] -> masked scores for this tile.
// red2 must be >= 4*130 floats of shared scratch. All 256 threads must enter.
__device__ __forceinline__ void pair_epilogue(float (&acc)[2][16], int t, int b, int i0, int j0,
                                              const int* __restrict__ A_init,
                                              const float* __restrict__ W2,
                                              const float* __restrict__ b2,
                                              const float* __restrict__ scsh,
                                              float* red2, float* __restrict__ s_buf) {
  const int l = t & 63, wv = t >> 6, o0 = wv * 16;
  float sp0 = 0.0f, sp1 = 0.0f;
#pragma unroll
  for (int oi = 0; oi < 16; ++oi) {
    const float sc = scsh[o0 + oi];
    const float sh = scsh[64 + o0 + oi];
    const float w2 = W2[o0 + oi];
    float h0 = fmaf(acc[0][oi], sc, sh); h0 = lrelu(h0);
    float h1 = fmaf(acc[1][oi], sc, sh); h1 = lrelu(h1);
    sp0 = fmaf(w2, h0, sp0);
    sp1 = fmaf(w2, h1, sp1);
  }
  *(float2*)&red2[wv * 130 + 2 * l] = make_float2(sp0, sp1);
  __syncthreads();
  if (t < 128) {
    const float s = red2[t] + red2[130 + t] + red2[260 + t] + red2[390 + t] + b2[0];
    const int il = t >> 3, jl = t & 7;
    const size_t arow = ((size_t)b * Nq + (i0 + il)) * Nq + (j0 + jl);
    s_buf[arow] = (A_init[arow] > 0) ? s : NEGq;
  }
}

// MODE 0: pass1 (BN stats [+ optional transposed h store]); MODE 1: pass2 recompute -> scores.
// Wave-uniform W1T slices (global, scalarizable s_load) keep LDS traffic to 1 b64/k/wave.
template <int MODE, bool WRITE_H>
__global__ __launch_bounds__(256, 3) void k_pair_core(
    const float* __restrict__ x, const float* __restrict__ W1Tg,
    const int* __restrict__ A_init, const float* __restrict__ W2,
    const float* __restrict__ b2, const float* __restrict__ scsh,
    float* __restrict__ partial1, float* __restrict__ h_buf,
    float* __restrict__ s_buf) {
  __shared__ float XI[TI][132];
  __shared__ float XJ[TJ][132];
  __shared__ float DtBuf[64 * 130];   // k-chunk x pairs (stride 130); reused as reduction scratch

  const int t = threadIdx.x;
  const int l = t & 63;
  const int wv = __builtin_amdgcn_readfirstlane(t >> 6);  // force wave-uniform
  const int o0 = wv * 16;
  const int jt = blockIdx.x, it = blockIdx.y, b = blockIdx.z;
  const int i0 = it * TI, j0 = jt * TJ;
  const float* xb = x + (size_t)b * Nq * Cq;

  // ---- stage XI, XJ ----
  {
    const int row = t >> 4, col = (t & 15) * 8;
    const float* src = xb + (size_t)(i0 + row) * Cq + col;
    *(float4*)&XI[row][col] = *(const float4*)src;
    *(float4*)&XI[row][col + 4] = *(const float4*)(src + 4);
    if (t < 128) {
      const int rj = t >> 4;
      const float* sj = xb + (size_t)(j0 + rj) * Cq + col;
      *(float4*)&XJ[rj][col] = *(const float4*)sj;
      *(float4*)&XJ[rj][col + 4] = *(const float4*)(sj + 4);
    }
  }
  __syncthreads();

  float acc[2][16];
#pragma unroll
  for (int pp = 0; pp < 2; ++pp)
#pragma unroll
    for (int oo = 0; oo < 16; ++oo) acc[pp][oo] = 0.0f;

  for (int chunk = 0; chunk < 2; ++chunk) {
    __syncthreads();
    // ---- phase A: stage |xi - xj| transposed: Dt[c][pair] ----
    {
      const int p = t & 127, cg = t >> 7;
      const int il = p >> 3, jl = p & 7;
      const float* xi = &XI[il][chunk * 64];
      const float* xj = &XJ[jl][chunk * 64];
#pragma unroll
      for (int m = 0; m < 8; ++m) {
        const int c0 = m * 8 + cg * 4;
        float4 a = *(const float4*)(xi + c0);
        float4 bb = *(const float4*)(xj + c0);
        DtBuf[(c0 + 0) * 130 + p] = fabsf(a.x - bb.x);
        DtBuf[(c0 + 1) * 130 + p] = fabsf(a.y - bb.y);
        DtBuf[(c0 + 2) * 130 + p] = fabsf(a.z - bb.z);
        DtBuf[(c0 + 3) * 130 + p] = fabsf(a.w - bb.w);
      }
    }
    __syncthreads();
    // ---- phase B: d from LDS (1x b64), W wave-uniform from global (s_load) ----
    const float* wbase = W1Tg + (size_t)(chunk * 64) * 64 + o0;
#pragma unroll 4
    for (int k = 0; k < 64; ++k) {
      const float2 d2 = *(const float2*)&DtBuf[k * 130 + 2 * l];
      const float* wr = wbase + (size_t)k * 64;
      const float4 w0 = *(const float4*)(wr + 0);
      const float4 w1 = *(const float4*)(wr + 4);
      const float4 w2v = *(const float4*)(wr + 8);
      const float4 w3 = *(const float4*)(wr + 12);
      const float w[16] = {w0.x, w0.y, w0.z, w0.w, w1.x, w1.y, w1.z, w1.w,
                           w2v.x, w2v.y, w2v.z, w2v.w, w3.x, w3.y, w3.z, w3.w};
#pragma unroll
      for (int oi = 0; oi < 16; ++oi) {
        acc[0][oi] = fmaf(d2.x, w[oi], acc[0][oi]);
        acc[1][oi] = fmaf(d2.y, w[oi], acc[1][oi]);
      }
    }
  }
  __syncthreads();  // all phase-B reads of DtBuf done; safe to reuse as scratch

  const int blk = ((b * (Nq / TI) + it) * (Nq / TJ) + jt);

  if (MODE == 1) {
    pair_epilogue(acc, t, b, i0, j0, A_init, W2, b2, scsh, DtBuf, s_buf);
    return;
  }

  // ---- MODE 0: optional transposed h store: hT[blk][o][pair] ----
  if (WRITE_H) {
    float* hb = h_buf + ((size_t)blk * Oq + o0) * NPAIR + 2 * l;
#pragma unroll
    for (int oi = 0; oi < 16; ++oi) {
      *(float2*)&hb[(size_t)oi * NPAIR] = make_float2(acc[0][oi], acc[1][oi]);
    }
  }
  // ---- stats: per-channel sum / sumsq of h_raw (bias-free) ----
  // scratch layout: red[32 rows][260]: rows 0..15 = sum(o0+oi), 16..31 = sumsq
  {
#pragma unroll
    for (int oi = 0; oi < 16; ++oi) {
      const float a0 = acc[0][oi], a1 = acc[1][oi];
      DtBuf[oi * 260 + wv * 64 + l] = a0 + a1;
      DtBuf[(16 + oi) * 260 + wv * 64 + l] = a0 * a0 + a1 * a1;
    }
  }
  __syncthreads();
  {
    const int cmb = t >> 1, half = t & 1;
    const int w4 = cmb >> 5, idx = cmb & 31;   // w4: which wave's outputs; idx: 0..15 sum, 16..31 sq
    const float* rp = &DtBuf[idx * 260 + w4 * 64 + half * 32];
    float s = 0.0f;
#pragma unroll
    for (int i = 0; i < 32; i += 4) {
      const float4 v = *(const float4*)(rp + i);
      s += v.x + v.y + v.z + v.w;
    }
    s += __shfl_xor(s, 1);
    if (half == 0) {
      const int o = w4 * 16 + (idx & 15), typ = idx >> 4;
      partial1[(size_t)blk * 128 + typ * 64 + o] = s;
    }
  }
}

// pass2 variant reading stored transposed h
__global__ __launch_bounds__(256) void k_pass2_fromH(
    const float* __restrict__ h_buf, const int* __restrict__ A_init,
    const float* __restrict__ W2, const float* __restrict__ b2,
    const float* __restrict__ scsh, float* __restrict__ s_buf) {
  __shared__ float red2[4 * 130];
  const int t = threadIdx.x;
  const int l = t & 63, wv = t >> 6, o0 = wv * 16;
  const int jt = blockIdx.x, it = blockIdx.y, b = blockIdx.z;
  const int i0 = it * TI, j0 = jt * TJ;
  const int blk = ((b * (Nq / TI) + it) * (Nq / TJ) + jt);
  const float* hb = h_buf + ((size_t)blk * Oq + o0) * NPAIR + 2 * l;
  float acc[2][16];
#pragma unroll
  for (int oi = 0; oi < 16; ++oi) {
    const float2 v = *(const float2*)&hb[(size_t)oi * NPAIR];
    acc[0][oi] = v.x;
    acc[1][oi] = v.y;
  }
  pair_epilogue(acc, t, b, i0, j0, A_init, W2, b2, scsh, red2, s_buf);
}

__global__ __launch_bounds__(256) void k_reduce1(const float* __restrict__ partial1,
                                                 double* __restrict__ red1) {
  __shared__ double sh[256];
  const int vi = blockIdx.x;
  const int t = threadIdx.x;
  double a = 0.0;
  for (int blk = t; blk < NBLK; blk += 256) a += (double)partial1[(size_t)blk * 128 + vi];
  sh[t] = a;
  __syncthreads();
  for (int off = 128; off > 0; off >>= 1) {
    if (t < off) sh[t] += sh[t + off];
    __syncthreads();
  }
  if (t == 0) red1[vi] = sh[0];
}

__global__ void k_finalize1(const double* __restrict__ red1, const float* __restrict__ g1,
                            const float* __restrict__ be1, float* __restrict__ scsh) {
  const int o = threadIdx.x;  // 64
  const double m_raw = red1[o] / PTOT;
  double var = red1[64 + o] / PTOT - m_raw * m_raw;
  if (var < 0.0) var = 0.0;
  const float scale = g1[o] / sqrtf((float)var + EPSq);
  scsh[o] = scale;
  scsh[64 + o] = be1[o] - (float)m_raw * scale;  // b1 cancels exactly
}

__global__ __launch_bounds__(256) void k_softmax(float* __restrict__ s) {
  __shared__ float r1[4];
  const size_t row = blockIdx.x;
  float* p = s + row * Nq;
  const int t = threadIdx.x;
  float2 v = *(float2*)&p[t * 2];
  float mx = fmaxf(v.x, v.y);
#pragma unroll
  for (int off = 32; off > 0; off >>= 1) mx = fmaxf(mx, __shfl_xor(mx, off));
  if ((t & 63) == 0) r1[t >> 6] = mx;
  __syncthreads();
  mx = fmaxf(fmaxf(r1[0], r1[1]), fmaxf(r1[2], r1[3]));
  const float e0 = expf(v.x - mx), e1 = expf(v.y - mx);
  float ss = e0 + e1;
#pragma unroll
  for (int off = 32; off > 0; off >>= 1) ss += __shfl_xor(ss, off);
  __syncthreads();
  if ((t & 63) == 0) r1[t >> 6] = ss;
  __syncthreads();
  const float tot = r1[0] + r1[1] + r1[2] + r1[3];
  float2 o2;
  o2.x = e0 / tot;
  o2.y = e1 / tot;
  *(float2*)&p[t * 2] = o2;
}

// 4 rows per block; A coefficients via wave-uniform (scalarizable) float4 loads.
__global__ __launch_bounds__(128) void k_yagg(const float* __restrict__ A,
                                              const float* __restrict__ x,
                                              float* __restrict__ y) {
  const int r0 = blockIdx.x * 4;          // global row base (b*N+i), same b for all 4
  const int b = r0 >> 9;
  const int t = threadIdx.x;              // channel
  const float* xb = x + (size_t)b * Nq * Cq + t;
  const float* Ar = A + (size_t)r0 * Nq;
  float acc0 = 0.0f, acc1 = 0.0f, acc2 = 0.0f, acc3 = 0.0f;
#pragma unroll 2
  for (int j = 0; j < Nq; j += 4) {
    const float4 c0 = *(const float4*)&Ar[j];
    const float4 c1 = *(const float4*)&Ar[Nq + j];
    const float4 c2 = *(const float4*)&Ar[2 * Nq + j];
    const float4 c3 = *(const float4*)&Ar[3 * Nq + j];
    const float x0 = xb[(size_t)j * Cq];
    const float x1 = xb[(size_t)(j + 1) * Cq];
    const float x2 = xb[(size_t)(j + 2) * Cq];
    const float x3 = xb[(size_t)(j + 3) * Cq];
    acc0 = fmaf(c0.x, x0, acc0); acc0 = fmaf(c0.y, x1, acc0);
    acc0 = fmaf(c0.z, x2, acc0); acc0 = fmaf(c0.w, x3, acc0);
    acc1 = fmaf(c1.x, x0, acc1); acc1 = fmaf(c1.y, x1, acc1);
    acc1 = fmaf(c1.z, x2, acc1); acc1 = fmaf(c1.w, x3, acc1);
    acc2 = fmaf(c2.x, x0, acc2); acc2 = fmaf(c2.y, x1, acc2);
    acc2 = fmaf(c2.z, x2, acc2); acc2 = fmaf(c2.w, x3, acc2);
    acc3 = fmaf(c3.x, x0, acc3); acc3 = fmaf(c3.y, x1, acc3);
    acc3 = fmaf(c3.z, x2, acc3); acc3 = fmaf(c3.w, x3, acc3);
  }
  y[(size_t)(r0 + 0) * Cq + t] = acc0;
  y[(size_t)(r0 + 1) * Cq + t] = acc1;
  y[(size_t)(r0 + 2) * Cq + t] = acc2;
  y[(size_t)(r0 + 3) * Cq + t] = acc3;
}

__global__ __launch_bounds__(256) void k_yfc(const float* __restrict__ y,
                                             const float* __restrict__ WgT,
                                             const float* __restrict__ bg,
                                             float* __restrict__ yfc,
                                             double* __restrict__ statsg) {
  __shared__ float Y[16][128];
  __shared__ float red[2][128][2];
  const int n0 = blockIdx.x * 16;
  const int t = threadIdx.x;
  {
    const int r = t >> 4, c = (t & 15) * 8;
    const float* src = y + (size_t)(n0 + r) * Cq + c;
    *(float4*)&Y[r][c] = *(const float4*)src;
    *(float4*)&Y[r][c + 4] = *(const float4*)(src + 4);
  }
  __syncthreads();
  const int rg = t >> 7, h = t & 127;
  const float bgv = bg[h];
  float ssum = 0.0f, ssq = 0.0f;
  for (int r = 0; r < 8; ++r) {
    const int row = rg * 8 + r;
    float acc = bgv;
#pragma unroll 4
    for (int c = 0; c < 128; ++c) acc = fmaf(Y[row][c], WgT[(size_t)c * 128 + h], acc);
    yfc[(size_t)(n0 + row) * 128 + h] = acc;
    ssum += acc;
    ssq += acc * acc;
  }
  red[rg][h][0] = ssum;
  red[rg][h][1] = ssq;
  __syncthreads();
  if (t < 128) {
    atomicAdd(&statsg[t], (double)(red[0][t][0] + red[1][t][0]));
    atomicAdd(&statsg[128 + t], (double)(red[0][t][1] + red[1][t][1]));
  }
}

__global__ void k_finalizeg(const double* __restrict__ statsg, const float* __restrict__ gg,
                            const float* __restrict__ beg, float* __restrict__ scg) {
  const int h = threadIdx.x;  // 128
  const double m = statsg[h] / (double)NROW;
  double var = statsg[128 + h] / (double)NROW - m * m;
  if (var < 0.0) var = 0.0;
  const float scale = gg[h] / sqrtf((float)var + EPSq);
  scg[h] = scale;
  scg[128 + h] = beg[h] - (float)m * scale;
}

__global__ __launch_bounds__(256) void k_out(const float* __restrict__ x,
                                             const float* __restrict__ yfc,
                                             const float* __restrict__ WtT,
                                             const float* __restrict__ bt,
                                             const float* __restrict__ scg,
                                             float* __restrict__ out) {
  __shared__ float X[16][128];
  __shared__ float Z[16][128];
  const int n0 = blockIdx.x * 16;
  const int t = threadIdx.x;
  {
    const int r = t >> 4, c = (t & 15) * 8;
    const float* xs = x + (size_t)(n0 + r) * 128 + c;
    *(float4*)&X[r][c] = *(const float4*)xs;
    *(float4*)&X[r][c + 4] = *(const float4*)(xs + 4);
    const float* ys = yfc + (size_t)(n0 + r) * 128 + c;
#pragma unroll
    for (int k = 0; k < 8; ++k) {
      const float z = fmaf(ys[k], scg[c + k], scg[128 + c + k]);
      Z[r][c + k] = lrelu(z);
    }
  }
  __syncthreads();
  const int rg = t >> 7, o = t & 127;
  const float btv = bt[o];
  for (int r = 0; r < 8; ++r) {
    const int row = rg * 8 + r;
    float acc = btv;
#pragma unroll 4
    for (int c = 0; c < 128; ++c) acc = fmaf(X[row][c], WtT[(size_t)c * 128 + o], acc);
#pragma unroll 4
    for (int c = 0; c < 128; ++c) acc = fmaf(Z[row][c], WtT[(size_t)(128 + c) * 128 + o], acc);
    out[(size_t)(n0 + row) * 128 + o] = acc;
  }
}

__global__ void k_transpose(const float* __restrict__ Wg, const float* __restrict__ Wt,
                            const float* __restrict__ W1, float* __restrict__ WgT,
                            float* __restrict__ WtT, float* __restrict__ W1Tg) {
  const int idx = blockIdx.x * 256 + threadIdx.x;
  if (idx < 128 * 128) {
    const int h = idx >> 7, c = idx & 127;
    WgT[(size_t)c * 128 + h] = Wg[idx];
  } else if (idx < 128 * 128 + 128 * 256) {
    const int k2 = idx - 128 * 128;
    const int o = k2 >> 8, k = k2 & 255;
    WtT[(size_t)k * 128 + o] = Wt[k2];
  } else if (idx < 128 * 128 + 128 * 256 + 64 * 128) {
    const int k2 = idx - (128 * 128 + 128 * 256);
    const int o = k2 >> 7, c = k2 & 127;
    W1Tg[(size_t)c * 64 + o] = W1[k2];
  }
}

extern "C" void kernel_launch(void* const* d_in, const int* in_sizes, int n_in,
                              void* d_out, int out_size, void* d_ws, size_t ws_size,
                              hipStream_t stream) {
  const float* x = (const float*)d_in[0];
  const int* A_init = (const int*)d_in[1];
  const float* W1 = (const float*)d_in[2];
  // d_in[3] = b1 (cancels in BN affine fold)
  const float* g1 = (const float*)d_in[4];
  const float* be1 = (const float*)d_in[5];
  const float* W2 = (const float*)d_in[6];
  const float* b2 = (const float*)d_in[7];
  const float* Wg = (const float*)d_in[8];
  const float* bg = (const float*)d_in[9];
  const float* gg = (const float*)d_in[10];
  const float* beg = (const float*)d_in[11];
  const float* Wt = (const float*)d_in[12];
  const float* bt = (const float*)d_in[13];
  float* out = (float*)d_out;

  char* ws = (char*)d_ws;
  if (ws_size < WS_BASIC) return;  // cannot run without basic scratch
  float* sA = (float*)(ws + OFF_S);
  float* yagg = (float*)(ws + OFF_YAGG);
  float* yfc = (float*)(ws + OFF_YFC);
  float* WgT = (float*)(ws + OFF_WGT);
  float* WtT = (float*)(ws + OFF_WTT);
  float* W1Tg = (float*)(ws + OFF_W1T);
  float* partial1 = (float*)(ws + OFF_PART1);
  double* red1 = (double*)(ws + OFF_RED1);
  float* scsh1 = (float*)(ws + OFF_SC1);
  double* statsg = (double*)(ws + OFF_STATSG);
  float* scg = (float*)(ws + OFF_SCG);
  float* h_buf = (float*)(ws + OFF_H);
  const bool useH = ws_size >= WS_WITH_H;

  hipMemsetAsync(ws + OFF_STATSG, 0, 2048, stream);
  k_transpose<<<224, 256, 0, stream>>>(Wg, Wt, W1, WgT, WtT, W1Tg);

  dim3 gpass(Nq / TJ, Nq / TI, Bq);  // 64 x 32 x 4
  if (useH)
    k_pair_core<0, true><<<gpass, 256, 0, stream>>>(x, W1Tg, A_init, W2, b2, scsh1,
                                                    partial1, h_buf, sA);
  else
    k_pair_core<0, false><<<gpass, 256, 0, stream>>>(x, W1Tg, A_init, W2, b2, scsh1,
                                                     partial1, h_buf, sA);
  k_reduce1<<<128, 256, 0, stream>>>(partial1, red1);
  k_finalize1<<<1, 64, 0, stream>>>(red1, g1, be1, scsh1);
  if (useH)
    k_pass2_fromH<<<gpass, 256, 0, stream>>>(h_buf, A_init, W2, b2, scsh1, sA);
  else
    k_pair_core<1, false><<<gpass, 256, 0, stream>>>(x, W1Tg, A_init, W2, b2, scsh1,
                                                     partial1, h_buf, sA);
  k_softmax<<<NROW, 256, 0, stream>>>(sA);
  k_yagg<<<NROW / 4, 128, 0, stream>>>(sA, x, yagg);
  k_yfc<<<NROW / 16, 256, 0, stream>>>(yagg, WgT, bg, yfc, statsg);
  k_finalizeg<<<1, 128, 0, stream>>>(statsg, gg, beg, scg);
  k_out<<<NROW / 16, 256, 0, stream>>>(x, yfc, WtT, bt, scg, out);
}

// Round 6
// 234.176 us; speedup vs baseline: 2.5866x; 2.5866x over previous
//
#include <hip/hip_runtime.h>
#include <hip/hip_bf16.h>
#include <math.h>

// Problem dims (fixed by reference)
#define Bq 4
#define Nq 512
#define Cq 128   // d_in
#define Oq 64    // d_mid
#define TI 16
#define TJ 8
#define NBLK (Bq*(Nq/TI)*(Nq/TJ))   // 8192 pair-blocks
#define PTOT ((double)Bq*Nq*Nq)     // 1048576 pairs (BN2d population)
#define NROW (Bq*Nq)                // 2048 rows
#define EPSq 1e-5f
#define NEGq -9e15f

typedef _Float16 half8 __attribute__((ext_vector_type(8)));
typedef float f32x4 __attribute__((ext_vector_type(4)));

// ---- workspace layout (bytes) ----
#define OFF_S       0u          // s / A in-place: 4 MiB
#define OFF_YAGG    4194304u    // [2048][128] f32
#define OFF_YFC     5242880u    // [2048][128] f32
#define OFF_WGT     6291456u    // WgT [128][128] f32 (c-major)
#define OFF_WTT     6356992u    // WtT [256][128] f32 (k-major)
#define OFF_WF      6488064u    // W1 fp16 in MFMA frag order [4ks][4nt][64lane][8e]
#define OFF_PART1   6504448u    // partial1 [8192][128] f32
#define OFF_RED1    10698752u   // double[128]
#define OFF_SC1     10699776u   // float scale1[64], shift1[64]
#define OFF_PARTG   10700288u   // partialg [256][256] f32
#define OFF_SCG     10962432u   // float scaleg[128], shiftg[128]
#define WS_NEED     10963456u

__device__ __forceinline__ float lrelu(float v) { return v >= 0.0f ? v : 0.01f * v; }

// ============================================================================
// Pair core: h[p,o] = sum_c |x_i - x_j|_c * W1[o,c]  via fp16 MFMA 16x16x32.
// Block: 128 pairs (16 i x 8 j) x 64 outputs x K=128. 4 waves; wave wv owns
// Mtiles {2wv, 2wv+1} (32 pairs) and all 4 Ntiles.
// A-frag: row = l&15 (pair within Mtile), k = 4*(l>>4)+e (e<4), 16+4*(l>>4)+e-4.
// B-frag: col = l&15 (output), same k map — preloaded from Wf (frag-order).
// (k-map need only MATCH between A and B: dot over k is permutation-invariant.)
// C/D: col = l&15 (output), row = 4*(l>>4)+reg (pair) [m89-verified].
// MODE 0: BN stats (sum/sumsq of raw h). MODE 1: normalized->lrelu->W2->mask.
// ============================================================================
template <int MODE>
__global__ __launch_bounds__(256, 3) void k_pair_mfma(
    const float* __restrict__ x, const _Float16* __restrict__ Wf,
    const int* __restrict__ A_init, const float* __restrict__ W2,
    const float* __restrict__ b2, const float* __restrict__ scsh,
    float* __restrict__ partial1, float* __restrict__ s_buf) {
  __shared__ float XI[TI][136];
  __shared__ float XJ[TJ][136];
  __shared__ float ep[4][2][64];   // MODE0 cross-wave stats
  __shared__ float ssc[128];       // MODE1 score bounce

  const int t = threadIdx.x;
  const int l = t & 63;
  const int wv = __builtin_amdgcn_readfirstlane(t >> 6);
  const int jt = blockIdx.x, it = blockIdx.y, b = blockIdx.z;
  const int i0 = it * TI, j0 = jt * TJ;
  const float* xb = x + (size_t)b * Nq * Cq;

  // ---- B-frags: 16 x half8 = 64 VGPR, coalesced dwordx4 loads ----
  half8 bf[16];
#pragma unroll
  for (int i = 0; i < 16; ++i)
    bf[i] = *(const half8*)&Wf[(size_t)(i * 64 + l) * 8];

  // ---- stage XI, XJ (pad 136 floats) ----
  {
    const int row = t >> 4, col = (t & 15) * 8;
    const float* src = xb + (size_t)(i0 + row) * Cq + col;
    *(float4*)&XI[row][col] = *(const float4*)src;
    *(float4*)&XI[row][col + 4] = *(const float4*)(src + 4);
    if (t < 128) {
      const int rj = t >> 4;
      const float* sj = xb + (size_t)(j0 + rj) * Cq + col;
      *(float4*)&XJ[rj][col] = *(const float4*)sj;
      *(float4*)&XJ[rj][col + 4] = *(const float4*)(sj + 4);
    }
  }
  __syncthreads();

  const int g = l >> 4;        // k-group 0..3
  const int cL = l & 15;
  const int jlan = l & 7;
  const int ilh = (l >> 3) & 1;

  f32x4 zero;
  zero[0] = 0.0f; zero[1] = 0.0f; zero[2] = 0.0f; zero[3] = 0.0f;
  f32x4 acc[2][4];
#pragma unroll
  for (int m = 0; m < 2; ++m)
#pragma unroll
    for (int n = 0; n < 4; ++n) acc[m][n] = zero;

#pragma unroll
  for (int ks = 0; ks < 4; ++ks) {
#pragma unroll
    for (int m = 0; m < 2; ++m) {
      const int mt = wv * 2 + m;
      const int il = mt * 2 + ilh;          // (mt*16 + cL) >> 3
      const int c0 = ks * 32 + 4 * g;
      const float4 a0 = *(const float4*)&XI[il][c0];
      const float4 a1 = *(const float4*)&XI[il][c0 + 16];
      const float4 v0 = *(const float4*)&XJ[jlan][c0];
      const float4 v1 = *(const float4*)&XJ[jlan][c0 + 16];
      half8 af;
      af[0] = (_Float16)fabsf(a0.x - v0.x);
      af[1] = (_Float16)fabsf(a0.y - v0.y);
      af[2] = (_Float16)fabsf(a0.z - v0.z);
      af[3] = (_Float16)fabsf(a0.w - v0.w);
      af[4] = (_Float16)fabsf(a1.x - v1.x);
      af[5] = (_Float16)fabsf(a1.y - v1.y);
      af[6] = (_Float16)fabsf(a1.z - v1.z);
      af[7] = (_Float16)fabsf(a1.w - v1.w);
#pragma unroll
      for (int n = 0; n < 4; ++n)
        acc[m][n] = __builtin_amdgcn_mfma_f32_16x16x32_f16(af, bf[ks * 4 + n],
                                                           acc[m][n], 0, 0, 0);
    }
  }

  const int blk = ((b * (Nq / TI) + it) * (Nq / TJ) + jt);

  if (MODE == 0) {
    // per-channel sum/sumsq over the wave's 32 pairs, then cross-wave via LDS
#pragma unroll
    for (int n = 0; n < 4; ++n) {
      float a = 0.0f, q = 0.0f;
#pragma unroll
      for (int m = 0; m < 2; ++m)
#pragma unroll
        for (int r = 0; r < 4; ++r) {
          const float v = acc[m][n][r];
          a += v;
          q += v * v;
        }
      a += __shfl_xor(a, 16); a += __shfl_xor(a, 32);
      q += __shfl_xor(q, 16); q += __shfl_xor(q, 32);
      if (l < 16) {
        ep[wv][0][n * 16 + l] = a;
        ep[wv][1][n * 16 + l] = q;
      }
    }
    __syncthreads();
    if (t < 128) {
      const int o = t & 63, typ = t >> 6;
      const float v = ep[0][typ][o] + ep[1][typ][o] + ep[2][typ][o] + ep[3][typ][o];
      partial1[(size_t)blk * 128 + typ * 64 + o] = v;
    }
    return;
  }

  // ---- MODE 1: BN-normalize -> lrelu -> dot W2 -> mask -> scores ----
  float sc[4], sh[4], w2[4];
#pragma unroll
  for (int n = 0; n < 4; ++n) {
    const int o = n * 16 + cL;
    sc[n] = scsh[o];
    sh[n] = scsh[64 + o];
    w2[n] = W2[o];
  }
  float sp[2][4];
#pragma unroll
  for (int m = 0; m < 2; ++m)
#pragma unroll
    for (int r = 0; r < 4; ++r) {
      float v = 0.0f;
#pragma unroll
      for (int n = 0; n < 4; ++n) {
        float h = fmaf(acc[m][n][r], sc[n], sh[n]);
        h = lrelu(h);
        v = fmaf(w2[n], h, v);
      }
      v += __shfl_xor(v, 1);
      v += __shfl_xor(v, 2);
      v += __shfl_xor(v, 4);
      v += __shfl_xor(v, 8);
      sp[m][r] = v;
    }
  if (cL == 0) {
#pragma unroll
    for (int m = 0; m < 2; ++m)
#pragma unroll
      for (int r = 0; r < 4; ++r) ssc[wv * 32 + m * 16 + 4 * g + r] = sp[m][r];
  }
  __syncthreads();
  if (t < 128) {
    const int il2 = t >> 3, jl2 = t & 7;
    const size_t arow = ((size_t)b * Nq + (i0 + il2)) * Nq + (j0 + jl2);
    s_buf[arow] = (A_init[arow] > 0) ? ssc[t] + b2[0] : NEGq;
  }
}

// ============================================================================
__global__ __launch_bounds__(256) void k_reduce1(const float* __restrict__ partial1,
                                                 double* __restrict__ red1) {
  __shared__ double sh[256];
  const int vi = blockIdx.x;
  const int t = threadIdx.x;
  double a = 0.0;
  for (int blk = t; blk < NBLK; blk += 256) a += (double)partial1[(size_t)blk * 128 + vi];
  sh[t] = a;
  __syncthreads();
  for (int off = 128; off > 0; off >>= 1) {
    if (t < off) sh[t] += sh[t + off];
    __syncthreads();
  }
  if (t == 0) red1[vi] = sh[0];
}

__global__ void k_finalize1(const double* __restrict__ red1, const float* __restrict__ g1,
                            const float* __restrict__ be1, float* __restrict__ scsh) {
  const int o = threadIdx.x;  // 64
  const double m_raw = red1[o] / PTOT;
  double var = red1[64 + o] / PTOT - m_raw * m_raw;
  if (var < 0.0) var = 0.0;
  const float scale = g1[o] / sqrtf((float)var + EPSq);
  scsh[o] = scale;
  scsh[64 + o] = be1[o] - (float)m_raw * scale;  // b1 cancels exactly
}

__global__ __launch_bounds__(256) void k_softmax(float* __restrict__ s) {
  __shared__ float r1[4];
  const size_t row = blockIdx.x;
  float* p = s + row * Nq;
  const int t = threadIdx.x;
  float2 v = *(float2*)&p[t * 2];
  float mx = fmaxf(v.x, v.y);
#pragma unroll
  for (int off = 32; off > 0; off >>= 1) mx = fmaxf(mx, __shfl_xor(mx, off));
  if ((t & 63) == 0) r1[t >> 6] = mx;
  __syncthreads();
  mx = fmaxf(fmaxf(r1[0], r1[1]), fmaxf(r1[2], r1[3]));
  const float e0 = expf(v.x - mx), e1 = expf(v.y - mx);
  float ss = e0 + e1;
#pragma unroll
  for (int off = 32; off > 0; off >>= 1) ss += __shfl_xor(ss, off);
  __syncthreads();
  if ((t & 63) == 0) r1[t >> 6] = ss;
  __syncthreads();
  const float tot = r1[0] + r1[1] + r1[2] + r1[3];
  float2 o2;
  o2.x = e0 / tot;
  o2.y = e1 / tot;
  *(float2*)&p[t * 2] = o2;
}

// 4 rows per block; A coefficients via wave-uniform (scalarizable) float4 loads.
__global__ __launch_bounds__(128) void k_yagg(const float* __restrict__ A,
                                              const float* __restrict__ x,
                                              float* __restrict__ y) {
  const int r0 = blockIdx.x * 4;
  const int b = r0 >> 9;
  const int t = threadIdx.x;              // channel
  const float* xb = x + (size_t)b * Nq * Cq + t;
  const float* Ar = A + (size_t)r0 * Nq;
  float acc0 = 0.0f, acc1 = 0.0f, acc2 = 0.0f, acc3 = 0.0f;
#pragma unroll 2
  for (int j = 0; j < Nq; j += 4) {
    const float4 c0 = *(const float4*)&Ar[j];
    const float4 c1 = *(const float4*)&Ar[Nq + j];
    const float4 c2 = *(const float4*)&Ar[2 * Nq + j];
    const float4 c3 = *(const float4*)&Ar[3 * Nq + j];
    const float x0 = xb[(size_t)j * Cq];
    const float x1 = xb[(size_t)(j + 1) * Cq];
    const float x2 = xb[(size_t)(j + 2) * Cq];
    const float x3 = xb[(size_t)(j + 3) * Cq];
    acc0 = fmaf(c0.x, x0, acc0); acc0 = fmaf(c0.y, x1, acc0);
    acc0 = fmaf(c0.z, x2, acc0); acc0 = fmaf(c0.w, x3, acc0);
    acc1 = fmaf(c1.x, x0, acc1); acc1 = fmaf(c1.y, x1, acc1);
    acc1 = fmaf(c1.z, x2, acc1); acc1 = fmaf(c1.w, x3, acc1);
    acc2 = fmaf(c2.x, x0, acc2); acc2 = fmaf(c2.y, x1, acc2);
    acc2 = fmaf(c2.z, x2, acc2); acc2 = fmaf(c2.w, x3, acc2);
    acc3 = fmaf(c3.x, x0, acc3); acc3 = fmaf(c3.y, x1, acc3);
    acc3 = fmaf(c3.z, x2, acc3); acc3 = fmaf(c3.w, x3, acc3);
  }
  y[(size_t)(r0 + 0) * Cq + t] = acc0;
  y[(size_t)(r0 + 1) * Cq + t] = acc1;
  y[(size_t)(r0 + 2) * Cq + t] = acc2;
  y[(size_t)(r0 + 3) * Cq + t] = acc3;
}

// 8 rows/block, 256 blocks: thread = (row, 4 h-outputs); W via coalesced float4.
__global__ __launch_bounds__(256) void k_yfc(const float* __restrict__ y,
                                             const float* __restrict__ WgT,
                                             const float* __restrict__ bg,
                                             float* __restrict__ yfc,
                                             float* __restrict__ partialg) {
  __shared__ float Y[8][128];
  __shared__ float red[2][8][128];
  const int n0 = blockIdx.x * 8;
  const int t = threadIdx.x;
  const int r = t >> 5, c4 = (t & 31) * 4;
  *(float4*)&Y[r][c4] = *(const float4*)&y[(size_t)(n0 + r) * 128 + c4];
  __syncthreads();
  const float4 bv = *(const float4*)&bg[c4];
  float a0 = bv.x, a1 = bv.y, a2 = bv.z, a3 = bv.w;
#pragma unroll 4
  for (int c = 0; c < 128; ++c) {
    const float yv = Y[r][c];
    const float4 w = *(const float4*)&WgT[(size_t)c * 128 + c4];
    a0 = fmaf(yv, w.x, a0);
    a1 = fmaf(yv, w.y, a1);
    a2 = fmaf(yv, w.z, a2);
    a3 = fmaf(yv, w.w, a3);
  }
  *(float4*)&yfc[(size_t)(n0 + r) * 128 + c4] = make_float4(a0, a1, a2, a3);
  red[0][r][c4] = a0; red[0][r][c4 + 1] = a1; red[0][r][c4 + 2] = a2; red[0][r][c4 + 3] = a3;
  red[1][r][c4] = a0 * a0; red[1][r][c4 + 1] = a1 * a1;
  red[1][r][c4 + 2] = a2 * a2; red[1][r][c4 + 3] = a3 * a3;
  __syncthreads();
  if (t < 128) {
    float s = 0.0f, q = 0.0f;
#pragma unroll
    for (int rr = 0; rr < 8; ++rr) { s += red[0][rr][t]; q += red[1][rr][t]; }
    partialg[(size_t)blockIdx.x * 256 + t] = s;
    partialg[(size_t)blockIdx.x * 256 + 128 + t] = q;
  }
}

__global__ void k_finalizeg(const float* __restrict__ partialg, const float* __restrict__ gg,
                            const float* __restrict__ beg, float* __restrict__ scg) {
  const int h = threadIdx.x;  // 128
  double s = 0.0, q = 0.0;
  for (int blk = 0; blk < 256; ++blk) {
    s += (double)partialg[(size_t)blk * 256 + h];
    q += (double)partialg[(size_t)blk * 256 + 128 + h];
  }
  const double m = s / (double)NROW;
  double var = q / (double)NROW - m * m;
  if (var < 0.0) var = 0.0;
  const float scale = gg[h] / sqrtf((float)var + EPSq);
  scg[h] = scale;
  scg[128 + h] = beg[h] - (float)m * scale;
}

__global__ __launch_bounds__(256) void k_out(const float* __restrict__ x,
                                             const float* __restrict__ yfc,
                                             const float* __restrict__ WtT,
                                             const float* __restrict__ bt,
                                             const float* __restrict__ scg,
                                             float* __restrict__ out) {
  __shared__ float XZ[8][256];
  const int n0 = blockIdx.x * 8;
  const int t = threadIdx.x;
  const int r = t >> 5, c4 = (t & 31) * 4;
  *(float4*)&XZ[r][c4] = *(const float4*)&x[(size_t)(n0 + r) * 128 + c4];
  {
    const float4 yv = *(const float4*)&yfc[(size_t)(n0 + r) * 128 + c4];
    const float4 s0 = *(const float4*)&scg[c4];
    const float4 s1 = *(const float4*)&scg[128 + c4];
    XZ[r][128 + c4 + 0] = lrelu(fmaf(yv.x, s0.x, s1.x));
    XZ[r][128 + c4 + 1] = lrelu(fmaf(yv.y, s0.y, s1.y));
    XZ[r][128 + c4 + 2] = lrelu(fmaf(yv.z, s0.z, s1.z));
    XZ[r][128 + c4 + 3] = lrelu(fmaf(yv.w, s0.w, s1.w));
  }
  __syncthreads();
  const float4 bv = *(const float4*)&bt[c4];
  float a0 = bv.x, a1 = bv.y, a2 = bv.z, a3 = bv.w;
#pragma unroll 4
  for (int c = 0; c < 256; ++c) {
    const float xv = XZ[r][c];
    const float4 w = *(const float4*)&WtT[(size_t)c * 128 + c4];
    a0 = fmaf(xv, w.x, a0);
    a1 = fmaf(xv, w.y, a1);
    a2 = fmaf(xv, w.z, a2);
    a3 = fmaf(xv, w.w, a3);
  }
  *(float4*)&out[(size_t)(n0 + r) * 128 + c4] = make_float4(a0, a1, a2, a3);
}

// WgT (c-major), WtT (k-major), Wf = W1 as fp16 in exact MFMA B-frag order.
__global__ void k_prep(const float* __restrict__ Wg, const float* __restrict__ Wt,
                       const float* __restrict__ W1, float* __restrict__ WgT,
                       float* __restrict__ WtT, _Float16* __restrict__ Wf) {
  const int idx = blockIdx.x * 256 + threadIdx.x;
  if (idx < 16384) {
    const int h = idx >> 7, c = idx & 127;
    WgT[(size_t)c * 128 + h] = Wg[idx];
  } else if (idx < 49152) {
    const int k2 = idx - 16384;
    const int o = k2 >> 8, k = k2 & 255;
    WtT[(size_t)k * 128 + o] = Wt[k2];
  } else if (idx < 57344) {
    const int f = idx - 49152;
    const int e = f & 7, lane = (f >> 3) & 63, nt = (f >> 9) & 3, ks = f >> 11;
    const int k = ks * 32 + 4 * (lane >> 4) + ((e < 4) ? e : (12 + e));  // +16 for hi half
    const int o = nt * 16 + (lane & 15);
    Wf[f] = (_Float16)W1[o * 128 + k];
  }
}

extern "C" void kernel_launch(void* const* d_in, const int* in_sizes, int n_in,
                              void* d_out, int out_size, void* d_ws, size_t ws_size,
                              hipStream_t stream) {
  const float* x = (const float*)d_in[0];
  const int* A_init = (const int*)d_in[1];
  const float* W1 = (const float*)d_in[2];
  // d_in[3] = b1 (cancels in BN affine fold)
  const float* g1 = (const float*)d_in[4];
  const float* be1 = (const float*)d_in[5];
  const float* W2 = (const float*)d_in[6];
  const float* b2 = (const float*)d_in[7];
  const float* Wg = (const float*)d_in[8];
  const float* bg = (const float*)d_in[9];
  const float* gg = (const float*)d_in[10];
  const float* beg = (const float*)d_in[11];
  const float* Wt = (const float*)d_in[12];
  const float* bt = (const float*)d_in[13];
  float* out = (float*)d_out;

  char* ws = (char*)d_ws;
  if (ws_size < WS_NEED) return;
  float* sA = (float*)(ws + OFF_S);
  float* yagg = (float*)(ws + OFF_YAGG);
  float* yfc = (float*)(ws + OFF_YFC);
  float* WgT = (float*)(ws + OFF_WGT);
  float* WtT = (float*)(ws + OFF_WTT);
  _Float16* Wf = (_Float16*)(ws + OFF_WF);
  float* partial1 = (float*)(ws + OFF_PART1);
  double* red1 = (double*)(ws + OFF_RED1);
  float* scsh1 = (float*)(ws + OFF_SC1);
  float* partialg = (float*)(ws + OFF_PARTG);
  float* scg = (float*)(ws + OFF_SCG);

  k_prep<<<224, 256, 0, stream>>>(Wg, Wt, W1, WgT, WtT, Wf);

  dim3 gpass(Nq / TJ, Nq / TI, Bq);  // 64 x 32 x 4
  k_pair_mfma<0><<<gpass, 256, 0, stream>>>(x, Wf, A_init, W2, b2, scsh1, partial1, sA);
  k_reduce1<<<128, 256, 0, stream>>>(partial1, red1);
  k_finalize1<<<1, 64, 0, stream>>>(red1, g1, be1, scsh1);
  k_pair_mfma<1><<<gpass, 256, 0, stream>>>(x, Wf, A_init, W2, b2, scsh1, partial1, sA);
  k_softmax<<<NROW, 256, 0, stream>>>(sA);
  k_yagg<<<NROW / 4, 128, 0, stream>>>(sA, x, yagg);
  k_yfc<<<NROW / 8, 256, 0, stream>>>(yagg, WgT, bg, yfc, partialg);
  k_finalizeg<<<1, 128, 0, stream>>>(partialg, gg, beg, scg);
  k_out<<<NROW / 8, 256, 0, stream>>>(x, yfc, WtT, bt, scg, out);
}